// Round 5
// baseline (657.963 us; speedup 1.0000x reference)
//
#include <hip/hip_runtime.h>
#include <hip/hip_bf16.h>
#include <math.h>

#define C 256
#define K 9
#define BM 64
#define NKSTEP 72          // 2304 / 32
#define HSTEPS 18          // 9 taps * 2 halves of 128 ch
#define NBUF 4             // gather prefetch distance 3

typedef __attribute__((ext_vector_type(8))) short bf16x8;
typedef __attribute__((ext_vector_type(4))) float f32x4;

__device__ __forceinline__ unsigned short f2bf(float f) {
    unsigned int u = __float_as_uint(f);
    unsigned int r = (u + 0x7fffu + ((u >> 16) & 1u)) >> 16;
    return (unsigned short)r;
}

__device__ __forceinline__ float gelu_exact(float x) {
    return 0.5f * x * (1.0f + erff(x * 0.70710678118654752f));
}

// ---- mask dtype auto-detect (proven R2/R3) ---------------------------------
__global__ void detect_mask_kernel(const unsigned char* __restrict__ mb, int nbytes,
                                   unsigned int* __restrict__ cnt) {
    unsigned int l0 = 0, l12 = 0;
    for (int i = blockIdx.x * blockDim.x + threadIdx.x; i < nbytes;
         i += blockDim.x * gridDim.x) {
        unsigned char v = mb[i];
        if (v) {
            int r = i & 3;
            if (r == 0) l0 = 1;
            else if (r < 3) l12 = 1;
        }
    }
    unsigned long long b0 = __ballot(l0 != 0);
    unsigned long long b1 = __ballot(l12 != 0);
    if ((threadIdx.x & 63) == 0) {
        if (b0) atomicOr(&cnt[0], 1u);
        if (b1) atomicOr(&cnt[1], 1u);
    }
}

// ---- feats fp32 -> bf16, vectorized (8/thread) -----------------------------
__global__ void convert_feats(const float* __restrict__ in, unsigned short* __restrict__ out, int n8) {
    int i = blockIdx.x * blockDim.x + threadIdx.x;
    if (i >= n8) return;
    const float4* p = (const float4*)(in + (size_t)i * 8);
    float4 a = p[0], b = p[1];
    uint4 v;
    v.x = (unsigned int)f2bf(a.x) | ((unsigned int)f2bf(a.y) << 16);
    v.y = (unsigned int)f2bf(a.z) | ((unsigned int)f2bf(a.w) << 16);
    v.z = (unsigned int)f2bf(b.x) | ((unsigned int)f2bf(b.y) << 16);
    v.w = (unsigned int)f2bf(b.z) | ((unsigned int)f2bf(b.w) << 16);
    *(uint4*)(out + (size_t)i * 8) = v;
}

// ---- pack W[K][C][C] fp32 -> bf16 MFMA B-fragment order (proven R3) --------
__global__ void pack_w(const float* __restrict__ W, unsigned short* __restrict__ Wp) {
    int id = blockIdx.x * blockDim.x + threadIdx.x;
    if (id >= NKSTEP * 16 * 64) return;
    int lane = id & 63;
    int ctg  = (id >> 6) & 15;
    int kkg  = id >> 10;
    int tap  = kkg >> 3;
    int c    = (kkg & 7) * 32 + ((lane >> 4) << 3);
    int d    = ctg * 16 + (lane & 15);
    const float* src = W + ((size_t)tap * C + c) * C + d;
    unsigned int w[4];
    #pragma unroll
    for (int i = 0; i < 4; ++i) {
        unsigned short lo = f2bf(src[(size_t)(2 * i) * C]);
        unsigned short hi = f2bf(src[(size_t)(2 * i + 1) * C]);
        w[i] = (unsigned int)lo | ((unsigned int)hi << 16);
    }
    uint4 v = {w[0], w[1], w[2], w[3]};
    *(uint4*)(Wp + (size_t)id * 8) = v;
}

// ---- fused sparse-conv (bf16 MFMA) + LN (+residual) + GELU -----------------
// Both phases gather bf16 rows (512 B) from gbase: zero page @0, rows @512+idx*512.
// 4-deep LDS rotation, prefetch distance 3. Per stage: barrier -> B-loads (so
// later compute waits never drain the staging queue: vmcnt is in-order) ->
// stage(s+3) -> ds_read+MFMA cluster under setprio.
template<int PHASE>
__global__ __launch_bounds__(256, 2)
void conv_mfma(const char* __restrict__ gbase,
               const unsigned short* __restrict__ Wp,
               const float* __restrict__ gamma, const float* __restrict__ beta,
               const int* __restrict__ nbr, const void* __restrict__ mask,
               const unsigned int* __restrict__ mflags,
               const float* __restrict__ resid,        // PHASE2: fp32 feats
               void* __restrict__ dst,                 // PHASE1: ushort* h1; PHASE2: float* out
               int N)
{
    __shared__ __align__(16) unsigned short Abuf[NBUF][BM * 128];  // 64 KB
    __shared__ unsigned int offs[K][BM];
    __shared__ float part[BM][8];

    const int tid  = threadIdx.x;
    const int lane = tid & 63;
    const int wv   = tid >> 6;
    const int n0   = blockIdx.x * BM;

    const bool mbool = (mflags[0] != 0u) && (mflags[1] != 0u);
    const unsigned char* mask8  = (const unsigned char*)mask;
    const unsigned int*  mask32 = (const unsigned int*)mask;
    for (int e = tid; e < K * BM; e += 256) {
        int tap = e >> 6;
        int r   = e & (BM - 1);
        int row = n0 + r;
        unsigned int off = 0u;                         // masked / OOB -> zero page
        if (row < N) {
            size_t ei = (size_t)row * K + tap;
            bool mv = mbool ? (mask8[ei] != 0) : (mask32[ei] != 0u);
            if (mv) off = 512u + (unsigned int)nbr[ei] * 512u;
        }
        offs[tap][r] = off;
    }

    f32x4 acc[4][4];
    #pragma unroll
    for (int rt = 0; rt < 4; ++rt)
        #pragma unroll
        for (int ct = 0; ct < 4; ++ct)
            acc[rt][ct] = (f32x4){0.f, 0.f, 0.f, 0.f};

    __syncthreads();                                   // offs visible to all

    // stage s (tap = s/2, 128-ch half = s%2) into buffer b: 4 loads/wave, 1 KB each.
    // LDS dest linear; swizzle baked into SOURCE (rule 21, involution with read XOR).
    auto stage = [&](int s, int b) {
        int tap = s >> 1, h = (s & 1) * 256;
        #pragma unroll
        for (int ii = 0; ii < 4; ++ii) {
            int i = wv * 4 + ii;                       // 0..15: 4 rows each
            int r = i * 4 + (lane >> 4);
            int c16s = ((lane & 15) ^ (r & 7)) * 16;
            const char* g = gbase + offs[tap][r] + h + c16s;
            __builtin_amdgcn_global_load_lds((const __attribute__((address_space(1))) void*)g,
                (__attribute__((address_space(3))) void*)(&Abuf[b][i * 512]), 16, 0, 0);
        }
    };

    // prologue: three stages in flight
    stage(0, 0);
    stage(1, 1);
    stage(2, 2);

    for (int s = 0; s < HSTEPS; ++s) {
        const int bs = s & 3;
        // own stage-s loads landed (8 newer = stages s+1, s+2 allowed outstanding)
        asm volatile("s_waitcnt vmcnt(8)" ::: "memory");
        __builtin_amdgcn_sched_barrier(0);
        __builtin_amdgcn_s_barrier();                  // raw: no vmcnt drain
        __builtin_amdgcn_sched_barrier(0);

        // 1. B fragments for this stage FIRST: all later waits target these,
        //    which are NEWER than staging loads -> staging stays in flight.
        bf16x8 bfr[4][4];
        #pragma unroll
        for (int kk = 0; kk < 4; ++kk)
            #pragma unroll
            for (int ct = 0; ct < 4; ++ct)
                bfr[kk][ct] = *(const bf16x8*)(Wp +
                    (((size_t)(s * 4 + kk) * 16 + (wv * 4 + ct)) * 64 + lane) * 8);
        __builtin_amdgcn_sched_barrier(0);

        // 2. staging for s+3 (youngest in queue; drained only by next iters' waits)
        if (s + 3 < HSTEPS) stage(s + 3, (s + 3) & 3);
        __builtin_amdgcn_sched_barrier(0);

        // 3. A fragments from LDS + 64 MFMA
        __builtin_amdgcn_s_setprio(1);
        #pragma unroll
        for (int kk = 0; kk < 4; ++kk) {
            bf16x8 afr[4];
            #pragma unroll
            for (int rt = 0; rt < 4; ++rt) {
                int r = rt * 16 + (lane & 15);
                int c16 = kk * 4 + (lane >> 4);
                afr[rt] = *(const bf16x8*)(&Abuf[bs][r * 128 + ((c16 ^ (r & 7)) * 8)]);
            }
            #pragma unroll
            for (int rt = 0; rt < 4; ++rt)
                #pragma unroll
                for (int ct = 0; ct < 4; ++ct)
                    acc[rt][ct] = __builtin_amdgcn_mfma_f32_16x16x32_bf16(
                        afr[rt], bfr[kk][ct], acc[rt][ct], 0, 0, 0);
        }
        __builtin_amdgcn_s_setprio(0);
        __builtin_amdgcn_sched_barrier(0);
    }

    // ---- LayerNorm partials ----
    #pragma unroll
    for (int rt = 0; rt < 4; ++rt) {
        #pragma unroll
        for (int jj = 0; jj < 4; ++jj) {
            float p1 = 0.f, p2 = 0.f;
            #pragma unroll
            for (int ct = 0; ct < 4; ++ct) {
                float v = acc[rt][ct][jj];
                p1 += v; p2 += v * v;
            }
            #pragma unroll
            for (int off = 1; off < 16; off <<= 1) {
                p1 += __shfl_xor(p1, off, 64);
                p2 += __shfl_xor(p2, off, 64);
            }
            if ((lane & 15) == 0) {
                int row = rt * 16 + (lane >> 4) * 4 + jj;
                part[row][wv * 2]     = p1;
                part[row][wv * 2 + 1] = p2;
            }
        }
    }
    __syncthreads();

    // ---- finalize: LN + (residual) + GELU + store ----
    float gm[4], bt[4];
    #pragma unroll
    for (int ct = 0; ct < 4; ++ct) {
        int col = wv * 64 + ct * 16 + (lane & 15);
        gm[ct] = gamma[col]; bt[ct] = beta[col];
    }
    const float inv_c = 1.0f / 256.0f;
    #pragma unroll
    for (int rt = 0; rt < 4; ++rt) {
        #pragma unroll
        for (int jj = 0; jj < 4; ++jj) {
            int row = rt * 16 + (lane >> 4) * 4 + jj;
            float t1 = part[row][0] + part[row][2] + part[row][4] + part[row][6];
            float t2 = part[row][1] + part[row][3] + part[row][5] + part[row][7];
            float mu  = t1 * inv_c;
            float var = t2 * inv_c - mu * mu;
            float rs  = rsqrtf(var + 1e-6f);
            int grow = n0 + row;
            if (grow < N) {
                #pragma unroll
                for (int ct = 0; ct < 4; ++ct) {
                    int col = wv * 64 + ct * 16 + (lane & 15);
                    float x = (acc[rt][ct][jj] - mu) * rs * gm[ct] + bt[ct];
                    if (PHASE == 2) x += resid[(size_t)grow * C + col];
                    float o = gelu_exact(x);
                    if (PHASE == 1) ((unsigned short*)dst)[(size_t)grow * C + col] = f2bf(o);
                    else            ((float*)dst)[(size_t)grow * C + col] = o;
                }
            }
        }
    }
}

extern "C" void kernel_launch(void* const* d_in, const int* in_sizes, int n_in,
                              void* d_out, int out_size, void* d_ws, size_t ws_size,
                              hipStream_t stream) {
    const float* feats = (const float*)d_in[0];
    const float* W1    = (const float*)d_in[1];
    const float* g1    = (const float*)d_in[2];
    const float* b1    = (const float*)d_in[3];
    const float* W2    = (const float*)d_in[4];
    const float* g2    = (const float*)d_in[5];
    const float* b2    = (const float*)d_in[6];
    const int*   nbr   = (const int*)d_in[7];
    const void*  mask  = (const void*)d_in[8];

    const int N = in_sizes[0] / C;

    // ws: [zero 512B][h1 bf16 N*C*2][Wp1][Wp2][flags]  (~54 MB, proven budget)
    char* ws = (char*)d_ws;
    unsigned short* h1  = (unsigned short*)(ws + 512);
    size_t h1_bytes = 512 + (size_t)N * C * 2;
    size_t wp_bytes = (size_t)NKSTEP * 16 * 64 * 16;
    unsigned short* Wp1 = (unsigned short*)(ws + h1_bytes);
    unsigned short* Wp2 = (unsigned short*)(ws + h1_bytes + wp_bytes);
    unsigned int* mflags = (unsigned int*)(ws + h1_bytes + 2 * wp_bytes);

    // d_out doubles as phase-1 gather arena: [zero 512B][featsb bf16 N*C*2];
    // phase 2 overwrites it with the final fp32 output.
    char* fzone = (char*)d_out;
    unsigned short* featsb = (unsigned short*)(fzone + 512);

    hipMemsetAsync(ws, 0, 512, stream);
    hipMemsetAsync(fzone, 0, 512, stream);
    hipMemsetAsync(mflags, 0, 2 * sizeof(unsigned int), stream);
    detect_mask_kernel<<<256, 256, 0, stream>>>((const unsigned char*)mask, N * K, mflags);
    convert_feats<<<(N * C / 8 + 255) / 256, 256, 0, stream>>>(feats, featsb, N * C / 8);
    pack_w<<<(NKSTEP * 16 * 64 + 255) / 256, 256, 0, stream>>>(W1, Wp1);
    pack_w<<<(NKSTEP * 16 * 64 + 255) / 256, 256, 0, stream>>>(W2, Wp2);

    const int grid = (N + BM - 1) / BM;
    conv_mfma<1><<<grid, 256, 0, stream>>>(fzone, Wp1, g1, b1, nbr, mask, mflags,
                                           nullptr, (void*)h1, N);
    conv_mfma<2><<<grid, 256, 0, stream>>>(ws, Wp2, g2, b2, nbr, mask, mflags,
                                           feats, d_out, N);
}